// Round 1
// baseline (596.628 us; speedup 1.0000x reference)
//
#include <hip/hip_runtime.h>
#include <stdint.h>

#define B_ 64
#define T_ 2048
#define H_ 512
#define U_ 512
#define BT 128
#define BK 32
#define BKPW 20   // uint32 words per padded LDS row (= 40 bf16: 32 data + 8 pad)

typedef short bf16x8 __attribute__((ext_vector_type(8)));
typedef float f32x4 __attribute__((ext_vector_type(4)));

static __device__ __forceinline__ uint32_t f2bf(float f) {
  uint32_t u = __float_as_uint(f);
  return (u + 0x7fffu + ((u >> 16) & 1u)) >> 16;   // RNE, inputs are normal floats
}
static __device__ __forceinline__ uint32_t pack2(float lo, float hi) {
  return f2bf(lo) | (f2bf(hi) << 16);
}
static __device__ __forceinline__ float fast_tanh(float x) {
  float z = fminf(fmaxf(x, -15.f), 15.f);
  float e = __expf(2.f * z);
  return (e - 1.f) / (e + 1.f);
}

// ---------------- kernel 1: P[b][u] = ([q|c] @ W1)[b][u] + b1[u] + b2[u] ----
__global__ void k_proj(const float* __restrict__ q, const float* __restrict__ c,
                       const float* __restrict__ W1, const float* __restrict__ b1,
                       const float* __restrict__ b2, float* __restrict__ P) {
  int u = (blockIdx.x & 1) * 256 + threadIdx.x;
  int b = blockIdx.x >> 1;
  const float* qr = q + b * H_;
  const float* cr = c + b * H_;
  float acc = 0.f;
  for (int k = 0; k < H_; ++k) acc = fmaf(qr[k], W1[k * U_ + u], acc);
  for (int k = 0; k < H_; ++k) acc = fmaf(cr[k], W1[(H_ + k) * U_ + u], acc);
  P[b * U_ + u] = acc + b1[u] + b2[u];
}

// ---------------- kernel 2: W2t[u][k] = bf16(W2[k][u]) ----------------------
__global__ void k_w2t(const float* __restrict__ W2, uint16_t* __restrict__ W2t) {
  int lin = blockIdx.x * 256 + threadIdx.x;   // grid 1024
  int u = lin >> 9, k = lin & 511;
  W2t[u * 512 + k] = (uint16_t)f2bf(W2[k * 512 + u]);
}

// ---------------- kernel 3: scores[b][t] = sum_u tanh(P[b][u]+ (vals@W2)[t][u]) * V[u] + bv
__global__ __launch_bounds__(512) void k_scores(
    const float* __restrict__ values, const uint16_t* __restrict__ W2t,
    const float* __restrict__ P, const float* __restrict__ Vw,
    const float* __restrict__ bv, float* __restrict__ scores) {

  __shared__ uint32_t ldsA[BT * BKPW];   // 10240 B
  __shared__ uint32_t ldsB[U_ * BKPW];   // 40960 B
  __shared__ float Pb[U_];
  __shared__ float Vb[U_];
  __shared__ float ssc[4][BT];

  const int tid = threadIdx.x;
  const int b = blockIdx.y;
  const int t0 = blockIdx.x * BT;
  const int lane = tid & 63;
  const int wid = tid >> 6;      // 8 waves
  const int wm = wid >> 2;       // 0..1  (row half: 64 t-rows)
  const int wn = wid & 3;        // 0..3  (col quarter: 128 u-cols)
  const int l15 = lane & 15;
  const int l4 = lane >> 4;      // 0..3

  Pb[tid & 511] = P[b * U_ + (tid & 511)];
  Vb[tid & 511] = Vw[tid & 511];

  f32x4 acc[4][8];
#pragma unroll
  for (int mt = 0; mt < 4; ++mt)
#pragma unroll
    for (int nt = 0; nt < 8; ++nt) acc[mt][nt] = (f32x4){0.f, 0.f, 0.f, 0.f};

  const float* Abase = values + ((size_t)b * T_ + t0) * H_;
  const uint32_t* Bsrc = (const uint32_t*)W2t;   // row stride 256 words

  for (int k0 = 0; k0 < H_; k0 += BK) {
    __syncthreads();   // previous iter's frag reads done before overwrite
    // stage A: values[t0..t0+127][k0..k0+31] fp32 -> bf16, 2048 pairs
    {
      int p = tid;
#pragma unroll
      for (int it = 0; it < 4; ++it, p += 512) {
        int t = p >> 4, kp = p & 15;
        const float2 v = *(const float2*)(Abase + t * H_ + k0 + kp * 2);
        ldsA[t * BKPW + kp] = pack2(v.x, v.y);
      }
      // stage B: W2t[0..511][k0..k0+31] (already bf16), 8192 words
      p = tid;
#pragma unroll
      for (int it = 0; it < 16; ++it, p += 512) {
        int u = p >> 4, kp = p & 15;
        ldsB[u * BKPW + kp] = Bsrc[u * (H_ / 2) + (k0 >> 1) + kp];
      }
    }
    __syncthreads();

    bf16x8 afr[4];
    const uint32_t* pa = &ldsA[(wm * 64 + l15) * BKPW + l4 * 4];
#pragma unroll
    for (int mt = 0; mt < 4; ++mt)
      afr[mt] = *(const bf16x8*)(pa + mt * 16 * BKPW);
    const uint32_t* pbp = &ldsB[(wn * 128 + l15) * BKPW + l4 * 4];
#pragma unroll
    for (int nt = 0; nt < 8; ++nt) {
      bf16x8 bfr = *(const bf16x8*)(pbp + nt * 16 * BKPW);
#pragma unroll
      for (int mt = 0; mt < 4; ++mt)
        acc[mt][nt] = __builtin_amdgcn_mfma_f32_16x16x32_bf16(afr[mt], bfr, acc[mt][nt], 0, 0, 0);
    }
  }

  // epilogue: spart[mt][r] = sum over this lane's 8 u-cols of tanh(P+acc)*V
  float spart[4][4];
#pragma unroll
  for (int mt = 0; mt < 4; ++mt)
#pragma unroll
    for (int r = 0; r < 4; ++r) spart[mt][r] = 0.f;

#pragma unroll
  for (int nt = 0; nt < 8; ++nt) {
    int u = wn * 128 + nt * 16 + l15;
    float pv = Pb[u], vv = Vb[u];
#pragma unroll
    for (int mt = 0; mt < 4; ++mt) {
#pragma unroll
      for (int r = 0; r < 4; ++r)
        spart[mt][r] += fast_tanh(pv + acc[mt][nt][r]) * vv;
    }
  }
  // butterfly over the 16 u-lanes (bits 0..3)
#pragma unroll
  for (int d = 1; d < 16; d <<= 1) {
#pragma unroll
    for (int mt = 0; mt < 4; ++mt)
#pragma unroll
      for (int r = 0; r < 4; ++r)
        spart[mt][r] += __shfl_xor(spart[mt][r], d);
  }
  if (l15 == 0) {
#pragma unroll
    for (int mt = 0; mt < 4; ++mt)
#pragma unroll
      for (int r = 0; r < 4; ++r)
        ssc[wn][wm * 64 + mt * 16 + l4 * 4 + r] = spart[mt][r];
  }
  __syncthreads();
  if (tid < BT) {
    float s = ssc[0][tid] + ssc[1][tid] + ssc[2][tid] + ssc[3][tid] + bv[0];
    scores[(size_t)b * T_ + t0 + tid] = s;
  }
}

// ---------------- kernel 4: softmax over T, in place ------------------------
__global__ void k_softmax(float* __restrict__ w) {
  __shared__ float red[4];
  __shared__ float red2[4];
  int b = blockIdx.x, tid = threadIdx.x;
  int lane = tid & 63, wid = tid >> 6;
  float* s = w + (size_t)b * T_;
  float v[8];
  float m = -1e30f;
#pragma unroll
  for (int j = 0; j < 8; ++j) { v[j] = s[tid + j * 256]; m = fmaxf(m, v[j]); }
#pragma unroll
  for (int d = 1; d < 64; d <<= 1) m = fmaxf(m, __shfl_xor(m, d));
  if (lane == 0) red[wid] = m;
  __syncthreads();
  m = fmaxf(fmaxf(red[0], red[1]), fmaxf(red[2], red[3]));
  float e[8];
  float sum = 0.f;
#pragma unroll
  for (int j = 0; j < 8; ++j) { e[j] = __expf(v[j] - m); sum += e[j]; }
#pragma unroll
  for (int d = 1; d < 64; d <<= 1) sum += __shfl_xor(sum, d);
  if (lane == 0) red2[wid] = sum;
  __syncthreads();
  sum = red2[0] + red2[1] + red2[2] + red2[3];
  float inv = 1.f / sum;
#pragma unroll
  for (int j = 0; j < 8; ++j) s[tid + j * 256] = e[j] * inv;
}

// ---------------- kernel 5: context[b][h] = sum_t w[b][t]*values[b][t][h] ---
__global__ void k_context(const float* __restrict__ values, const float* __restrict__ w,
                          float* __restrict__ ctx) {
  int b = blockIdx.z;
  int h = blockIdx.y * 256 + threadIdx.x;
  int t0 = blockIdx.x * 128;
  const float* wb = w + (size_t)b * T_ + t0;
  const float* vb = values + ((size_t)b * T_ + t0) * H_ + h;
  float acc = 0.f;
#pragma unroll 4
  for (int t = 0; t < 128; ++t) acc = fmaf(wb[t], vb[(size_t)t * H_], acc);
  atomicAdd(&ctx[b * H_ + h], acc);
}

extern "C" void kernel_launch(void* const* d_in, const int* in_sizes, int n_in,
                              void* d_out, int out_size, void* d_ws, size_t ws_size,
                              hipStream_t stream) {
  const float* query = (const float*)d_in[0];
  const float* cell  = (const float*)d_in[1];
  const float* values = (const float*)d_in[2];
  const float* W1 = (const float*)d_in[3];
  const float* b1 = (const float*)d_in[4];
  const float* W2 = (const float*)d_in[5];
  const float* b2 = (const float*)d_in[6];
  const float* Vw = (const float*)d_in[7];
  const float* bv = (const float*)d_in[8];

  float* out = (float*)d_out;                    // [0,32768): context ; [32768,163840): weights
  float* wgt = out + B_ * H_;

  char* ws = (char*)d_ws;
  float* P = (float*)ws;                         // 131072 B
  uint16_t* W2t = (uint16_t*)(ws + 131072);      // 524288 B

  hipMemsetAsync(out, 0, B_ * H_ * sizeof(float), stream);   // zero context accumulators
  k_proj<<<128, 256, 0, stream>>>(query, cell, W1, b1, b2, P);
  k_w2t<<<1024, 256, 0, stream>>>(W2, W2t);
  k_scores<<<dim3(T_ / BT, B_), 512, 0, stream>>>(values, W2t, P, Vw, bv, wgt);
  k_softmax<<<B_, 256, 0, stream>>>(wgt);
  k_context<<<dim3(T_ / 128, H_ / 256, B_), 256, 0, stream>>>(values, wgt, out);
}

// Round 2
// 539.388 us; speedup vs baseline: 1.1061x; 1.1061x over previous
//
#include <hip/hip_runtime.h>
#include <stdint.h>

#define B_ 64
#define T_ 2048
#define H_ 512
#define U_ 512
#define BT 128
#define BK 32
#define KT 16   // H_/BK

typedef short bf16x8 __attribute__((ext_vector_type(8)));
typedef float f32x4 __attribute__((ext_vector_type(4)));

static __device__ __forceinline__ uint32_t f2bf(float f) {
  uint32_t u = __float_as_uint(f);
  return (u + 0x7fffu + ((u >> 16) & 1u)) >> 16;   // RNE
}
static __device__ __forceinline__ uint32_t pack2(float lo, float hi) {
  return f2bf(lo) | (f2bf(hi) << 16);
}
static __device__ __forceinline__ float fast_tanh(float x) {
  float z = fminf(fmaxf(x, -15.f), 15.f);
  float e = __expf(2.f * z);
  return (e - 1.f) / (e + 1.f);
}

// ---------------- kernel 1: P[b][u] = ([q|c] @ W1)[b][u] + b1[u] + b2[u] ----
__global__ void k_proj(const float* __restrict__ q, const float* __restrict__ c,
                       const float* __restrict__ W1, const float* __restrict__ b1,
                       const float* __restrict__ b2, float* __restrict__ P) {
  int u = (blockIdx.x & 1) * 256 + threadIdx.x;
  int b = blockIdx.x >> 1;
  const float* qr = q + b * H_;
  const float* cr = c + b * H_;
  float acc = 0.f;
  for (int k = 0; k < H_; ++k) acc = fmaf(qr[k], W1[k * U_ + u], acc);
  for (int k = 0; k < H_; ++k) acc = fmaf(cr[k], W1[(H_ + k) * U_ + u], acc);
  P[b * U_ + u] = acc + b1[u] + b2[u];
}

// ---------------- kernel 2: wsB[cg][u][4w] = bf16 pairs of W2[cg*8+2j..+1][u]
// Fragment-order B so k_scores can global_load_lds it linearly.
__global__ void k_w2b(const float* __restrict__ W2, uint32_t* __restrict__ wsB) {
  int lin = blockIdx.x * 256 + threadIdx.x;   // 32768 threads: cg(64) x u(512)
  int u = lin & 511, cg = lin >> 9;
  int k = cg * 8;
  uint32_t w0 = pack2(W2[(k + 0) * U_ + u], W2[(k + 1) * U_ + u]);
  uint32_t w1 = pack2(W2[(k + 2) * U_ + u], W2[(k + 3) * U_ + u]);
  uint32_t w2 = pack2(W2[(k + 4) * U_ + u], W2[(k + 5) * U_ + u]);
  uint32_t w3 = pack2(W2[(k + 6) * U_ + u], W2[(k + 7) * U_ + u]);
  *(uint4*)(wsB + (size_t)lin * 4) = make_uint4(w0, w1, w2, w3);
}

// ---------------- kernel 3: scores[b][t] = sum_u tanh(P[b][u]+(vals@W2)[t][u])*V[u]
// 2-phase double-buffered MFMA pipeline, tile 128t x 512u, BK=32.
__global__ __launch_bounds__(512, 2) void k_scores(
    const float* __restrict__ values, const uint32_t* __restrict__ wsB,
    const float* __restrict__ P, const float* __restrict__ Vw,
    float* __restrict__ scores) {

  // LDS layout: [buf][kg(4)][row][8 bf16] -> word idx = kg*ROWS*4 + row*4 + w
  __shared__ uint32_t lA[2][2048];   // 4kg x 128t x 4w  = 16 KB
  __shared__ uint32_t lB[2][8192];   // 4kg x 512u x 4w  = 64 KB
  __shared__ float Pb[U_];
  __shared__ float Vb[U_];
  __shared__ float ssc[4][BT];

  const int tid = threadIdx.x;
  const int b = blockIdx.y;
  const int t0 = blockIdx.x * BT;
  const int lane = tid & 63;
  const int wid = tid >> 6;      // 8 waves
  const int wm = wid >> 2;       // t-half (64 rows)
  const int wn = wid & 3;        // u-quarter (128 cols)
  const int l15 = lane & 15;
  const int l4 = lane >> 4;

  Pb[tid] = P[b * U_ + tid];
  Vb[tid] = Vw[tid];

  const float* Abase = values + ((size_t)b * T_ + t0) * H_;
  const int sa_t = tid & 127;    // A-staging row
  const int sa_kg = tid >> 7;    // A-staging k-group

  f32x4 acc[4][8];
#pragma unroll
  for (int mt = 0; mt < 4; ++mt)
#pragma unroll
    for (int nt = 0; nt < 8; ++nt) acc[mt][nt] = (f32x4){0.f, 0.f, 0.f, 0.f};

  // ---- prologue: stage tile 0 into buf 0
  {
#pragma unroll
    for (int i = 0; i < 4; ++i)
      __builtin_amdgcn_global_load_lds(wsB + i * 2048 + tid * 4,
                                       &lB[0][i * 2048 + tid * 4], 16, 0, 0);
    const float4* ap = (const float4*)(Abase + (size_t)sa_t * H_ + sa_kg * 8);
    float4 x = ap[0], y = ap[1];
    *(uint4*)&lA[0][sa_kg * 512 + sa_t * 4] =
        make_uint4(pack2(x.x, x.y), pack2(x.z, x.w), pack2(y.x, y.y), pack2(y.z, y.w));
  }
  __syncthreads();

  int buf = 0;
  for (int kt = 0; kt < KT; ++kt) {
    const int nb = buf ^ 1;
    float4 x, y;
    if (kt < KT - 1) {
      const int kn = kt + 1;
      const float4* ap = (const float4*)(Abase + (size_t)sa_t * H_ + kn * BK + sa_kg * 8);
      x = ap[0]; y = ap[1];                       // prefetch A (VGPR)
      const uint32_t* bsrc = wsB + (size_t)kn * 8192;
#pragma unroll
      for (int i = 0; i < 4; ++i)                 // prefetch B (direct to LDS)
        __builtin_amdgcn_global_load_lds(bsrc + i * 2048 + tid * 4,
                                         &lB[nb][i * 2048 + tid * 4], 16, 0, 0);
    }
    // fragments + MFMA from current buffer
    bf16x8 afr[4];
#pragma unroll
    for (int mt = 0; mt < 4; ++mt)
      afr[mt] = *(const bf16x8*)&lA[buf][l4 * 512 + (wm * 64 + mt * 16 + l15) * 4];
#pragma unroll
    for (int nt = 0; nt < 8; ++nt) {
      bf16x8 bfr = *(const bf16x8*)&lB[buf][l4 * 2048 + (wn * 128 + nt * 16 + l15) * 4];
#pragma unroll
      for (int mt = 0; mt < 4; ++mt)
        acc[mt][nt] = __builtin_amdgcn_mfma_f32_16x16x32_bf16(afr[mt], bfr, acc[mt][nt], 0, 0, 0);
    }
    if (kt < KT - 1) {
      *(uint4*)&lA[nb][sa_kg * 512 + sa_t * 4] =
          make_uint4(pack2(x.x, x.y), pack2(x.z, x.w), pack2(y.x, y.y), pack2(y.z, y.w));
    }
    __syncthreads();   // drains vmcnt (B gll) + lgkm (A write) -> nb ready
    buf = nb;
  }

  // ---- epilogue: score partials = sum_u tanh(P+acc)*V
  float spart[4][4];
#pragma unroll
  for (int mt = 0; mt < 4; ++mt)
#pragma unroll
    for (int r = 0; r < 4; ++r) spart[mt][r] = 0.f;

#pragma unroll
  for (int nt = 0; nt < 8; ++nt) {
    int u = wn * 128 + nt * 16 + l15;
    float pv = Pb[u], vv = Vb[u];
#pragma unroll
    for (int mt = 0; mt < 4; ++mt)
#pragma unroll
      for (int r = 0; r < 4; ++r)
        spart[mt][r] += fast_tanh(pv + acc[mt][nt][r]) * vv;
  }
#pragma unroll
  for (int d = 1; d < 16; d <<= 1)
#pragma unroll
    for (int mt = 0; mt < 4; ++mt)
#pragma unroll
      for (int r = 0; r < 4; ++r)
        spart[mt][r] += __shfl_xor(spart[mt][r], d);

  if (l15 == 0) {
#pragma unroll
    for (int mt = 0; mt < 4; ++mt)
#pragma unroll
      for (int r = 0; r < 4; ++r)
        ssc[wn][wm * 64 + mt * 16 + l4 * 4 + r] = spart[mt][r];
  }
  __syncthreads();
  if (tid < BT) {
    float s = ssc[0][tid] + ssc[1][tid] + ssc[2][tid] + ssc[3][tid];
    scores[(size_t)b * T_ + t0 + tid] = s;   // bv dropped: softmax shift-invariant
  }
}

// ---------------- kernel 4: softmax over T, in place ------------------------
__global__ void k_softmax(float* __restrict__ w) {
  __shared__ float red[4];
  __shared__ float red2[4];
  int b = blockIdx.x, tid = threadIdx.x;
  int lane = tid & 63, wid = tid >> 6;
  float* s = w + (size_t)b * T_;
  float v[8];
  float m = -1e30f;
#pragma unroll
  for (int j = 0; j < 8; ++j) { v[j] = s[tid + j * 256]; m = fmaxf(m, v[j]); }
#pragma unroll
  for (int d = 1; d < 64; d <<= 1) m = fmaxf(m, __shfl_xor(m, d));
  if (lane == 0) red[wid] = m;
  __syncthreads();
  m = fmaxf(fmaxf(red[0], red[1]), fmaxf(red[2], red[3]));
  float e[8];
  float sum = 0.f;
#pragma unroll
  for (int j = 0; j < 8; ++j) { e[j] = __expf(v[j] - m); sum += e[j]; }
#pragma unroll
  for (int d = 1; d < 64; d <<= 1) sum += __shfl_xor(sum, d);
  if (lane == 0) red2[wid] = sum;
  __syncthreads();
  sum = red2[0] + red2[1] + red2[2] + red2[3];
  float inv = 1.f / sum;
#pragma unroll
  for (int j = 0; j < 8; ++j) s[tid + j * 256] = e[j] * inv;
}

// ---------------- kernel 5: context[b][h] = sum_t w[b][t]*values[b][t][h] ---
__global__ __launch_bounds__(256) void k_context(const float* __restrict__ values,
                                                 const float* __restrict__ w,
                                                 float* __restrict__ ctx) {
  int b = blockIdx.y;
  int t0 = blockIdx.x * 128;
  int tid = threadIdx.x;
  const float* wb = w + (size_t)b * T_ + t0;
  const float2* vb = (const float2*)(values + ((size_t)b * T_ + t0) * H_) + tid;
  float ax = 0.f, ay = 0.f;
#pragma unroll 8
  for (int t = 0; t < 128; ++t) {
    float ww = wb[t];
    float2 v = vb[(size_t)t * 256];
    ax = fmaf(ww, v.x, ax);
    ay = fmaf(ww, v.y, ay);
  }
  atomicAdd(&ctx[b * H_ + tid * 2], ax);
  atomicAdd(&ctx[b * H_ + tid * 2 + 1], ay);
}

extern "C" void kernel_launch(void* const* d_in, const int* in_sizes, int n_in,
                              void* d_out, int out_size, void* d_ws, size_t ws_size,
                              hipStream_t stream) {
  const float* query = (const float*)d_in[0];
  const float* cell  = (const float*)d_in[1];
  const float* values = (const float*)d_in[2];
  const float* W1 = (const float*)d_in[3];
  const float* b1 = (const float*)d_in[4];
  const float* W2 = (const float*)d_in[5];
  const float* b2 = (const float*)d_in[6];
  const float* Vw = (const float*)d_in[7];
  // d_in[8] (bv) intentionally unused: softmax is shift-invariant.

  float* out = (float*)d_out;                  // [0,32768): context ; then weights
  float* wgt = out + B_ * H_;

  char* ws = (char*)d_ws;
  float* P = (float*)ws;                       // 131072 B
  uint32_t* wsB = (uint32_t*)(ws + 131072);    // 524288 B, fragment-ordered W2

  hipMemsetAsync(out, 0, B_ * H_ * sizeof(float), stream);   // zero context accum
  k_proj<<<128, 256, 0, stream>>>(query, cell, W1, b1, b2, P);
  k_w2b<<<128, 256, 0, stream>>>(W2, wsB);
  k_scores<<<dim3(T_ / BT, B_), 512, 0, stream>>>(values, wsB, P, Vw, wgt);
  k_softmax<<<B_, 256, 0, stream>>>(wgt);
  k_context<<<dim3(T_ / 128, B_), 256, 0, stream>>>(values, wgt, out);
}